// Round 6
// baseline (360.789 us; speedup 1.0000x reference)
//
#include <hip/hip_runtime.h>

#define NPG 100     // nodes per graph
#define HF 64       // hidden width
#define NROW 128    // node rows padded to 4 x 32 tiles
#define SA 120      // Arm row stride (bf16): 112 k-slots + 8 pad
#define ST 72       // T row stride (bf16): 64 + 8 pad
#define CMW 28      // count-matrix words per row (112 u8 cols)

typedef float  f4   __attribute__((ext_vector_type(4)));
typedef float  f16v __attribute__((ext_vector_type(16)));
typedef short  bf8  __attribute__((ext_vector_type(8)));

#define SZ_ARM (NROW * SA * 2)        // 30720
#define SZ_T   (NROW * ST * 2)        // 18432
#define OFF_ARM 0
#define OFF_T   SZ_ARM                // 30720
#define OFF_CM  SZ_ARM                // u8 counts [128][28 u32] = 14336, overlays T (setup only)
#define OFF_MISC (OFF_T + SZ_T)       // 49152
#define SMEM_BYTES (OFF_MISC + 1280)  // 50432 -> 3 blocks/CU (151296 < 163840)

// bf16 weight workspace (d_ws), layout Wt[k5][fo][fi]:
//   W1t [5][64][16] @ 0  (fi zero-padded 3->16)
//   W2t [5][64][64] @ 5120
//   W3t [5][64][64] @ 25600
#define WT_TOTAL 46080

__device__ __forceinline__ unsigned short f2bf(float f) {
    unsigned u = __float_as_uint(f);
    u += 0x7fffu + ((u >> 16) & 1u);   // round-to-nearest-even
    return (unsigned short)(u >> 16);
}
__device__ __forceinline__ float bf2f(unsigned short h) {
    return __uint_as_float(((unsigned)h) << 16);
}
__device__ __forceinline__ f16v zerov16() {
    f16v z;
    #pragma unroll
    for (int i = 0; i < 16; i++) z[i] = 0.f;
    return z;
}

__global__ void wconv(const float* __restrict__ W1, const float* __restrict__ W2,
                      const float* __restrict__ W3, unsigned short* __restrict__ ws)
{
    int idx = blockIdx.x * 256 + threadIdx.x;
    if (idx >= WT_TOTAL) return;
    float v;
    if (idx < 5120) {
        int k5 = idx >> 10, rem = idx & 1023, fo = rem >> 4, fi = rem & 15;
        v = (fi < 3) ? W1[(k5 * 3 + fi) * HF + fo] : 0.f;
    } else if (idx < 25600) {
        int j = idx - 5120;
        int k5 = j >> 12, rem = j & 4095, fo = rem >> 6, fi = rem & 63;
        v = W2[(k5 * HF + fi) * HF + fo];
    } else {
        int j = idx - 25600;
        int k5 = j >> 12, rem = j & 4095, fo = rem >> 6, fi = rem & 63;
        v = W3[(k5 * HF + fi) * HF + fo];
    }
    ws[idx] = f2bf(v);
}

// One block per graph, 256 threads = 4 waves, 3 blocks/CU.
// Single in-place row-major T; per stage each wave register-stages its B-columns
// (T[k][fo], its own fo set) before the barrier, then writes in place after.
// LHAT: C[n'][f] = sum_n Arm[n'][n] * T[n][f]  (A=Arm rows b128, B=reg-staged cols)
// TW:   O[n'][fo] += sum_fi T[n'][fi] * Wt[fo][fi] (A=T rows b128, B=Wt b128)
// C/D: col = lane&31 (=f/fo), row = (r&3)+8*(r>>2)+4*(lane>>5) (=n' within tile)
// Cheb prev/old in packed-bf16 registers at the fixed (n', fo) lane positions.
__launch_bounds__(256, 3)
__global__ void cheb1b(const float* __restrict__ x, const int* __restrict__ ei,
                       const float* __restrict__ lambda_max,
                       const unsigned short* __restrict__ Wt,
                       const float* __restrict__ b1, const float* __restrict__ b2,
                       const float* __restrict__ b3,
                       const float* __restrict__ bng, const float* __restrict__ bnb,
                       const float* __restrict__ bnm, const float* __restrict__ bnv,
                       const float* __restrict__ fc1w, const float* __restrict__ fc1b,
                       const float* __restrict__ fc2w, const float* __restrict__ fc2b,
                       float* __restrict__ out, int E_total, int epg)
{
    extern __shared__ char sm[];
    const int tid = threadIdx.x;
    const int g = blockIdx.x;
    const int ebase = g * epg, nbase = g * NPG;
    const int wg = tid >> 6, lane = tid & 63;
    const int l31 = lane & 31, hh = lane >> 5;
    const int ht  = wg & 1;          // f-tile: cols 32*ht..+31
    const int Mt0 = (wg >> 1) * 2;   // n'-tile pair base
    const int fo  = ht * 32 + l31;

    unsigned* Cm  = (unsigned*)(sm + OFF_CM);
    float* dis    = (float*)(sm + OFF_MISC);          // 448 B
    float* pool   = (float*)(sm + OFF_MISC + 448);    // 256 B
    float* gvn    = (float*)(sm + OFF_MISC + 704);    // 256 B
    float* zf     = (float*)(sm + OFF_MISC + 960);    // 128 B
    float* logits = (float*)(sm + OFF_MISC + 1088);   // 64 B
    float* lsep   = (float*)(sm + OFF_MISC + 1152);

    const float lam = lambda_max[g];
    const float two_l = 2.0f / lam;
    const float cl = two_l - 1.0f;

    // ---------------- build dense Lhat directly in bf16 via u8 counts ----------------
    for (int i = tid; i < (NROW * CMW) / 4; i += 256)
        ((f4*)Cm)[i] = (f4){0.f, 0.f, 0.f, 0.f};
    __syncthreads();
    for (int e = tid; e < epg; e += 256) {
        int r = ei[ebase + e] - nbase;
        int c = ei[E_total + ebase + e] - nbase;
        atomicAdd(&Cm[r * CMW + (c >> 2)], 1u << (8 * (c & 3)));
    }
    __syncthreads();
    if (tid < NPG) {
        unsigned s = 0;
        #pragma unroll
        for (int w = 0; w < CMW; w++) {
            unsigned u = Cm[tid * CMW + w];
            s += (u & 255) + ((u >> 8) & 255) + ((u >> 16) & 255) + (u >> 24);
        }
        dis[tid] = s > 0 ? rsqrtf((float)s) : 0.f;
    }
    __syncthreads();
    for (int u = tid; u < NROW * 56; u += 256) {
        int n = u / 56, p = (u % 56) * 2;
        float v0 = 0.f, v1 = 0.f;
        if (n < NPG) {
            unsigned w = Cm[n * CMW + (p >> 2)];
            int sh = 8 * (p & 3);
            float c0 = (float)((w >> sh) & 255);
            float c1 = (float)((w >> (sh + 8)) & 255);
            float base = -two_l * dis[n];
            v0 = (p     < NPG) ? c0 * base * dis[p]     : 0.f;
            v1 = (p + 1 < NPG) ? c1 * base * dis[p + 1] : 0.f;
            if (p == n)     v0 += cl;
            if (p + 1 == n) v1 += cl;
        }
        *(unsigned*)(sm + OFF_ARM + (n * SA + p) * 2) =
            (unsigned)f2bf(v0) | ((unsigned)f2bf(v1) << 16);
    }
    __syncthreads();   // Cm reads done before T (overlay) is zeroed

    // ---------------- init T: zero + x ----------------
    for (int i = tid; i < SZ_T / 16; i += 256)
        ((f4*)(sm + OFF_T))[i] = (f4){0.f, 0.f, 0.f, 0.f};
    if (tid < HF) pool[tid] = 0.f;
    __syncthreads();
    if (tid < NPG) {
        unsigned short h0 = f2bf(x[(nbase + tid) * 3 + 0]);
        unsigned short h1 = f2bf(x[(nbase + tid) * 3 + 1]);
        unsigned short h2 = f2bf(x[(nbase + tid) * 3 + 2]);
        *(unsigned*)(sm + OFF_T + (tid * ST) * 2) = (unsigned)h0 | ((unsigned)h1 << 16);
        *(unsigned short*)(sm + OFF_T + (tid * ST + 2) * 2) = h2;
    }
    __syncthreads();

    // ---------------- 3 ChebConv layers ----------------
    f16v acc[2];
    unsigned prev[2][8], oldr[2][8];   // packed-bf16 T_{s-1}, T_{s-2} at (n', fo) lane positions
    const float* bsv[3] = {b1, b2, b3};

    for (int L = 0; L < 3; L++) {
        const bool l1 = (L == 0);
        const unsigned short* Wl = l1 ? Wt : (Wt + (L == 1 ? 5120 : 25600));
        acc[0] = zerov16();
        acc[1] = zerov16();

        // prev = T0 at C-layout positions
        #pragma unroll
        for (int m = 0; m < 2; m++) {
            unsigned short tv[16];
            #pragma unroll
            for (int r = 0; r < 16; r++) {
                int np = (Mt0 + m) * 32 + (r & 3) + 8 * (r >> 2) + 4 * hh;
                tv[r] = *(const unsigned short*)(sm + OFF_T + (np * ST + fo) * 2);
            }
            #pragma unroll
            for (int p = 0; p < 8; p++)
                prev[m][p] = (unsigned)tv[2 * p] | ((unsigned)tv[2 * p + 1] << 16);
        }

        auto TW = [&](int k5) {
            const int nKs = l1 ? 1 : 4;
            for (int Ks = 0; Ks < nKs; Ks++) {
                bf8 bw;
                if (l1) bw = *(const bf8*)(Wl + (k5 * 64 + fo) * 16 + 8 * hh);
                else    bw = *(const bf8*)(Wl + (k5 * 64 + fo) * 64 + Ks * 16 + 8 * hh);
                #pragma unroll
                for (int m = 0; m < 2; m++) {
                    bf8 a = *(const bf8*)(sm + OFF_T +
                              (((Mt0 + m) * 32 + l31) * ST + Ks * 16 + 8 * hh) * 2);
                    acc[m] = __builtin_amdgcn_mfma_f32_32x32x16_bf16(a, bw, acc[m], 0, 0, 0);
                }
            }
        };

        TW(0);
        for (int s = 1; s <= 4; s++) {
            // register-stage B: this wave's fo column, all 112 k rows
            bf8 bfr[7];
            #pragma unroll
            for (int Ks = 0; Ks < 7; Ks++) {
                #pragma unroll
                for (int j = 0; j < 8; j++) {
                    int k = Ks * 16 + 8 * hh + j;
                    bfr[Ks][j] = *(const short*)(sm + OFF_T + (k * ST + fo) * 2);
                }
            }
            __syncthreads();   // all T reads (TW(s-1), prev-init, bfr) done
            #pragma unroll
            for (int m = 0; m < 2; m++) {
                f16v c = zerov16();
                #pragma unroll
                for (int Ks = 0; Ks < 7; Ks++) {
                    bf8 a = *(const bf8*)(sm + OFF_ARM +
                              (((Mt0 + m) * 32 + l31) * SA + Ks * 16 + 8 * hh) * 2);
                    c = __builtin_amdgcn_mfma_f32_32x32x16_bf16(a, bfr[Ks], c, 0, 0, 0);
                }
                unsigned short h[16];
                #pragma unroll
                for (int r = 0; r < 16; r++) {
                    float v = c[r];
                    if (s >= 2) {
                        unsigned short o = (unsigned short)
                            ((oldr[m][r >> 1] >> (16 * (r & 1))) & 0xffff);
                        v = 2.f * v - bf2f(o);
                    }
                    h[r] = f2bf(v);
                }
                #pragma unroll
                for (int p = 0; p < 8; p++) {
                    oldr[m][p] = prev[m][p];
                    prev[m][p] = (unsigned)h[2 * p] | ((unsigned)h[2 * p + 1] << 16);
                }
                #pragma unroll
                for (int r = 0; r < 16; r++) {
                    int np = (Mt0 + m) * 32 + (r & 3) + 8 * (r >> 2) + 4 * hh;
                    *(unsigned short*)(sm + OFF_T + (np * ST + fo) * 2) = h[r];
                }
            }
            __syncthreads();   // writes visible before TW(s)
            TW(s);
        }
        __syncthreads();       // TW(4) reads done before epilogue writes

        const float bias = bsv[L][fo];
        if (L < 2) {
            #pragma unroll
            for (int m = 0; m < 2; m++) {
                #pragma unroll
                for (int r = 0; r < 16; r++) {
                    float h = fmaxf(acc[m][r] + bias, 0.f);
                    int np = (Mt0 + m) * 32 + (r & 3) + 8 * (r >> 2) + 4 * hh;
                    *(unsigned short*)(sm + OFF_T + (np * ST + fo) * 2) = f2bf(h);
                }
            }
            __syncthreads();
        } else {
            float ssum = 0.f;
            #pragma unroll
            for (int m = 0; m < 2; m++) {
                #pragma unroll
                for (int r = 0; r < 16; r++) {
                    int np = (Mt0 + m) * 32 + (r & 3) + 8 * (r >> 2) + 4 * hh;
                    float h = fmaxf(acc[m][r] + bias, 0.f);
                    if (np < NPG) ssum += h;
                }
            }
            ssum += __shfl_xor(ssum, 32, 64);
            if (hh == 0) atomicAdd(&pool[fo], ssum);
            __syncthreads();
        }
    }

    // ---------------- BN + MLP + log_softmax ----------------
    if (tid < HF) {
        float gv = pool[tid] * (1.0f / NPG);
        gv = (gv - bnm[tid]) * rsqrtf(bnv[tid] + 1e-5f) * bng[tid] + bnb[tid];
        gvn[tid] = gv;
    }
    __syncthreads();
    if (tid < 32) {
        float a = fc1b[tid];
        for (int f = 0; f < HF; f++) a += gvn[f] * fc1w[f * 32 + tid];
        zf[tid] = fmaxf(a, 0.f);
    }
    __syncthreads();
    if (tid < 10) {
        float a = fc2b[tid];
        for (int k = 0; k < 32; k++) a += zf[k] * fc2w[k * 10 + tid];
        logits[tid] = a;
    }
    __syncthreads();
    if (tid == 0) {
        float m = logits[0];
        for (int i = 1; i < 10; i++) m = fmaxf(m, logits[i]);
        float s = 0.f;
        for (int i = 0; i < 10; i++) s += expf(logits[i] - m);
        lsep[0] = m + logf(s);
    }
    __syncthreads();
    if (tid < 10) out[g * 10 + tid] = logits[tid] - lsep[0];
}

extern "C" void kernel_launch(void* const* d_in, const int* in_sizes, int n_in,
                              void* d_out, int out_size, void* d_ws, size_t ws_size,
                              hipStream_t stream) {
    const float* x    = (const float*)d_in[0];
    const int*   ei   = (const int*)d_in[1];
    const float* lmax = (const float*)d_in[3];
    const float* W1   = (const float*)d_in[4];
    const float* b1   = (const float*)d_in[5];
    const float* W2   = (const float*)d_in[6];
    const float* b2   = (const float*)d_in[7];
    const float* W3   = (const float*)d_in[8];
    const float* b3   = (const float*)d_in[9];
    const float* bng  = (const float*)d_in[10];
    const float* bnb  = (const float*)d_in[11];
    const float* bnm  = (const float*)d_in[12];
    const float* bnv  = (const float*)d_in[13];
    const float* fc1w = (const float*)d_in[14];
    const float* fc1b = (const float*)d_in[15];
    const float* fc2w = (const float*)d_in[16];
    const float* fc2b = (const float*)d_in[17];

    const int E = in_sizes[1] / 2;
    const int G = in_sizes[3];
    const int epg = E / G;

    unsigned short* Wt = (unsigned short*)d_ws;

    wconv<<<(WT_TOTAL + 255) / 256, 256, 0, stream>>>(W1, W2, W3, Wt);

    hipFuncSetAttribute((const void*)cheb1b,
                        hipFuncAttributeMaxDynamicSharedMemorySize, SMEM_BYTES);

    cheb1b<<<G, 256, SMEM_BYTES, stream>>>(x, ei, lmax, Wt, b1, b2, b3,
                                           bng, bnb, bnm, bnv, fc1w, fc1b, fc2w, fc2b,
                                           (float*)d_out, E, epg);
}

// Round 7
// 184.865 us; speedup vs baseline: 1.9516x; 1.9516x over previous
//
#include <hip/hip_runtime.h>

#define NPG 100     // nodes per graph
#define HF 64       // hidden width
#define NROW 128    // node rows padded to 4 x 32 tiles
#define SA 120      // Arm row stride (bf16): 112 k-slots + 8 pad
#define ST 72       // T row stride (bf16): 64 + 8 pad
#define CMW 28      // count-matrix words per row (112 u8 cols)

typedef float  f4   __attribute__((ext_vector_type(4)));
typedef float  f16v __attribute__((ext_vector_type(16)));
typedef short  bf8  __attribute__((ext_vector_type(8)));

#define SZ_ARM (NROW * SA * 2)        // 30720
#define SZ_T   (NROW * ST * 2)        // 18432
#define OFF_ARM 0
#define OFF_T   SZ_ARM                // 30720
#define OFF_CM  SZ_ARM                // u8 counts [128][28 u32] = 14336, overlays T (setup only)
#define OFF_MISC (OFF_T + SZ_T)       // 49152
#define SMEM_BYTES (OFF_MISC + 1280)  // 50432 -> LDS allows 3 blocks/CU (151296 < 163840)

// bf16 weight workspace (d_ws), layout Wt[k5][fo][fi]:
//   W1t [5][64][16] @ 0  (fi zero-padded 3->16)
//   W2t [5][64][64] @ 5120
//   W3t [5][64][64] @ 25600
#define WT_TOTAL 46080

__device__ __forceinline__ unsigned short f2bf(float f) {
    unsigned u = __float_as_uint(f);
    u += 0x7fffu + ((u >> 16) & 1u);   // round-to-nearest-even
    return (unsigned short)(u >> 16);
}
__device__ __forceinline__ float bf2f(unsigned short h) {
    return __uint_as_float(((unsigned)h) << 16);
}
__device__ __forceinline__ f16v zerov16() {
    f16v z;
    #pragma unroll
    for (int i = 0; i < 16; i++) z[i] = 0.f;
    return z;
}

__global__ void wconv(const float* __restrict__ W1, const float* __restrict__ W2,
                      const float* __restrict__ W3, unsigned short* __restrict__ ws)
{
    int idx = blockIdx.x * 256 + threadIdx.x;
    if (idx >= WT_TOTAL) return;
    float v;
    if (idx < 5120) {
        int k5 = idx >> 10, rem = idx & 1023, fo = rem >> 4, fi = rem & 15;
        v = (fi < 3) ? W1[(k5 * 3 + fi) * HF + fo] : 0.f;
    } else if (idx < 25600) {
        int j = idx - 5120;
        int k5 = j >> 12, rem = j & 4095, fo = rem >> 6, fi = rem & 63;
        v = W2[(k5 * HF + fi) * HF + fo];
    } else {
        int j = idx - 25600;
        int k5 = j >> 12, rem = j & 4095, fo = rem >> 6, fi = rem & 63;
        v = W3[(k5 * HF + fi) * HF + fo];
    }
    ws[idx] = f2bf(v);
}

// One block per graph, 256 threads = 4 waves.
// __launch_bounds__(256,2): R6 showed (256,3) caps VGPRs at ~84 -> catastrophic
// scratch spill (317 MB FETCH). (256,2) gives cap 256; body needs ~112 VGPRs ->
// HW occupancy = min(LDS 3 blocks, VGPR 4 waves/SIMD) = 3 blocks/CU, spill-free.
// Single in-place row-major T; per stage each wave register-stages its B-columns
// (T[k][fo]) before the barrier, then writes in place after.
// LHAT: C[n'][f] = sum_n Arm[n'][n] * T[n][f]  (A=Arm rows b128, B=reg-staged cols)
// TW:   O[n'][fo] += sum_fi T[n'][fi] * Wt[fo][fi] (A=T rows b128, B=Wt b128)
// C/D: col = lane&31 (=f/fo), row = (r&3)+8*(r>>2)+4*(lane>>5) (=n' within tile)
// Cheb prev/old in packed-bf16 registers at the fixed (n', fo) lane positions.
__launch_bounds__(256, 2)
__global__ void cheb1b(const float* __restrict__ x, const int* __restrict__ ei,
                       const float* __restrict__ lambda_max,
                       const unsigned short* __restrict__ Wt,
                       const float* __restrict__ b1, const float* __restrict__ b2,
                       const float* __restrict__ b3,
                       const float* __restrict__ bng, const float* __restrict__ bnb,
                       const float* __restrict__ bnm, const float* __restrict__ bnv,
                       const float* __restrict__ fc1w, const float* __restrict__ fc1b,
                       const float* __restrict__ fc2w, const float* __restrict__ fc2b,
                       float* __restrict__ out, int E_total, int epg)
{
    extern __shared__ char sm[];
    const int tid = threadIdx.x;
    const int g = blockIdx.x;
    const int ebase = g * epg, nbase = g * NPG;
    const int wg = tid >> 6, lane = tid & 63;
    const int l31 = lane & 31, hh = lane >> 5;
    const int ht  = wg & 1;          // f-tile: cols 32*ht..+31
    const int Mt0 = (wg >> 1) * 2;   // n'-tile pair base
    const int fo  = ht * 32 + l31;

    unsigned* Cm  = (unsigned*)(sm + OFF_CM);
    float* dis    = (float*)(sm + OFF_MISC);          // 448 B
    float* pool   = (float*)(sm + OFF_MISC + 448);    // 256 B
    float* gvn    = (float*)(sm + OFF_MISC + 704);    // 256 B
    float* zf     = (float*)(sm + OFF_MISC + 960);    // 128 B
    float* logits = (float*)(sm + OFF_MISC + 1088);   // 64 B
    float* lsep   = (float*)(sm + OFF_MISC + 1152);

    const float lam = lambda_max[g];
    const float two_l = 2.0f / lam;
    const float cl = two_l - 1.0f;

    // ---------------- build dense Lhat directly in bf16 via u8 counts ----------------
    for (int i = tid; i < (NROW * CMW) / 4; i += 256)
        ((f4*)Cm)[i] = (f4){0.f, 0.f, 0.f, 0.f};
    __syncthreads();
    for (int e = tid; e < epg; e += 256) {
        int r = ei[ebase + e] - nbase;
        int c = ei[E_total + ebase + e] - nbase;
        atomicAdd(&Cm[r * CMW + (c >> 2)], 1u << (8 * (c & 3)));
    }
    __syncthreads();
    if (tid < NPG) {
        unsigned s = 0;
        #pragma unroll
        for (int w = 0; w < CMW; w++) {
            unsigned u = Cm[tid * CMW + w];
            s += (u & 255) + ((u >> 8) & 255) + ((u >> 16) & 255) + (u >> 24);
        }
        dis[tid] = s > 0 ? rsqrtf((float)s) : 0.f;
    }
    __syncthreads();
    for (int u = tid; u < NROW * 56; u += 256) {
        int n = u / 56, p = (u % 56) * 2;
        float v0 = 0.f, v1 = 0.f;
        if (n < NPG) {
            unsigned w = Cm[n * CMW + (p >> 2)];
            int sh = 8 * (p & 3);
            float c0 = (float)((w >> sh) & 255);
            float c1 = (float)((w >> (sh + 8)) & 255);
            float base = -two_l * dis[n];
            v0 = (p     < NPG) ? c0 * base * dis[p]     : 0.f;
            v1 = (p + 1 < NPG) ? c1 * base * dis[p + 1] : 0.f;
            if (p == n)     v0 += cl;
            if (p + 1 == n) v1 += cl;
        }
        *(unsigned*)(sm + OFF_ARM + (n * SA + p) * 2) =
            (unsigned)f2bf(v0) | ((unsigned)f2bf(v1) << 16);
    }
    __syncthreads();   // Cm reads done before T (overlay) is zeroed

    // ---------------- init T: zero + x ----------------
    for (int i = tid; i < SZ_T / 16; i += 256)
        ((f4*)(sm + OFF_T))[i] = (f4){0.f, 0.f, 0.f, 0.f};
    if (tid < HF) pool[tid] = 0.f;
    __syncthreads();
    if (tid < NPG) {
        unsigned short h0 = f2bf(x[(nbase + tid) * 3 + 0]);
        unsigned short h1 = f2bf(x[(nbase + tid) * 3 + 1]);
        unsigned short h2 = f2bf(x[(nbase + tid) * 3 + 2]);
        *(unsigned*)(sm + OFF_T + (tid * ST) * 2) = (unsigned)h0 | ((unsigned)h1 << 16);
        *(unsigned short*)(sm + OFF_T + (tid * ST + 2) * 2) = h2;
    }
    __syncthreads();

    // ---------------- 3 ChebConv layers ----------------
    f16v acc[2];
    unsigned prev[2][8], oldr[2][8];   // packed-bf16 T_{s-1}, T_{s-2} at (n', fo) lane positions
    const float* bsv[3] = {b1, b2, b3};

    for (int L = 0; L < 3; L++) {
        const bool l1 = (L == 0);
        const unsigned short* Wl = l1 ? Wt : (Wt + (L == 1 ? 5120 : 25600));
        acc[0] = zerov16();
        acc[1] = zerov16();

        // prev = T0 at C-layout positions
        #pragma unroll
        for (int m = 0; m < 2; m++) {
            unsigned short tv[16];
            #pragma unroll
            for (int r = 0; r < 16; r++) {
                int np = (Mt0 + m) * 32 + (r & 3) + 8 * (r >> 2) + 4 * hh;
                tv[r] = *(const unsigned short*)(sm + OFF_T + (np * ST + fo) * 2);
            }
            #pragma unroll
            for (int p = 0; p < 8; p++)
                prev[m][p] = (unsigned)tv[2 * p] | ((unsigned)tv[2 * p + 1] << 16);
        }

        auto TW = [&](int k5) {
            const int nKs = l1 ? 1 : 4;
            for (int Ks = 0; Ks < nKs; Ks++) {
                bf8 bw;
                if (l1) bw = *(const bf8*)(Wl + (k5 * 64 + fo) * 16 + 8 * hh);
                else    bw = *(const bf8*)(Wl + (k5 * 64 + fo) * 64 + Ks * 16 + 8 * hh);
                #pragma unroll
                for (int m = 0; m < 2; m++) {
                    bf8 a = *(const bf8*)(sm + OFF_T +
                              (((Mt0 + m) * 32 + l31) * ST + Ks * 16 + 8 * hh) * 2);
                    acc[m] = __builtin_amdgcn_mfma_f32_32x32x16_bf16(a, bw, acc[m], 0, 0, 0);
                }
            }
        };

        TW(0);
        for (int s = 1; s <= 4; s++) {
            // register-stage B: this wave's fo column, all 112 k rows
            bf8 bfr[7];
            #pragma unroll
            for (int Ks = 0; Ks < 7; Ks++) {
                #pragma unroll
                for (int j = 0; j < 8; j++) {
                    int k = Ks * 16 + 8 * hh + j;
                    bfr[Ks][j] = *(const short*)(sm + OFF_T + (k * ST + fo) * 2);
                }
            }
            __syncthreads();   // all T reads (TW(s-1), prev-init, bfr) done
            #pragma unroll
            for (int m = 0; m < 2; m++) {
                f16v c = zerov16();
                #pragma unroll
                for (int Ks = 0; Ks < 7; Ks++) {
                    bf8 a = *(const bf8*)(sm + OFF_ARM +
                              (((Mt0 + m) * 32 + l31) * SA + Ks * 16 + 8 * hh) * 2);
                    c = __builtin_amdgcn_mfma_f32_32x32x16_bf16(a, bfr[Ks], c, 0, 0, 0);
                }
                unsigned short h[16];
                #pragma unroll
                for (int r = 0; r < 16; r++) {
                    float v = c[r];
                    if (s >= 2) {
                        unsigned short o = (unsigned short)
                            ((oldr[m][r >> 1] >> (16 * (r & 1))) & 0xffff);
                        v = 2.f * v - bf2f(o);
                    }
                    h[r] = f2bf(v);
                }
                #pragma unroll
                for (int p = 0; p < 8; p++) {
                    oldr[m][p] = prev[m][p];
                    prev[m][p] = (unsigned)h[2 * p] | ((unsigned)h[2 * p + 1] << 16);
                }
                #pragma unroll
                for (int r = 0; r < 16; r++) {
                    int np = (Mt0 + m) * 32 + (r & 3) + 8 * (r >> 2) + 4 * hh;
                    *(unsigned short*)(sm + OFF_T + (np * ST + fo) * 2) = h[r];
                }
            }
            __syncthreads();   // writes visible before TW(s)
            TW(s);
        }
        __syncthreads();       // TW(4) reads done before epilogue writes

        const float bias = bsv[L][fo];
        if (L < 2) {
            #pragma unroll
            for (int m = 0; m < 2; m++) {
                #pragma unroll
                for (int r = 0; r < 16; r++) {
                    float h = fmaxf(acc[m][r] + bias, 0.f);
                    int np = (Mt0 + m) * 32 + (r & 3) + 8 * (r >> 2) + 4 * hh;
                    *(unsigned short*)(sm + OFF_T + (np * ST + fo) * 2) = f2bf(h);
                }
            }
            __syncthreads();
        } else {
            float ssum = 0.f;
            #pragma unroll
            for (int m = 0; m < 2; m++) {
                #pragma unroll
                for (int r = 0; r < 16; r++) {
                    int np = (Mt0 + m) * 32 + (r & 3) + 8 * (r >> 2) + 4 * hh;
                    float h = fmaxf(acc[m][r] + bias, 0.f);
                    if (np < NPG) ssum += h;
                }
            }
            ssum += __shfl_xor(ssum, 32, 64);
            if (hh == 0) atomicAdd(&pool[fo], ssum);
            __syncthreads();
        }
    }

    // ---------------- BN + MLP + log_softmax ----------------
    if (tid < HF) {
        float gv = pool[tid] * (1.0f / NPG);
        gv = (gv - bnm[tid]) * rsqrtf(bnv[tid] + 1e-5f) * bng[tid] + bnb[tid];
        gvn[tid] = gv;
    }
    __syncthreads();
    if (tid < 32) {
        float a = fc1b[tid];
        for (int f = 0; f < HF; f++) a += gvn[f] * fc1w[f * 32 + tid];
        zf[tid] = fmaxf(a, 0.f);
    }
    __syncthreads();
    if (tid < 10) {
        float a = fc2b[tid];
        for (int k = 0; k < 32; k++) a += zf[k] * fc2w[k * 10 + tid];
        logits[tid] = a;
    }
    __syncthreads();
    if (tid == 0) {
        float m = logits[0];
        for (int i = 1; i < 10; i++) m = fmaxf(m, logits[i]);
        float s = 0.f;
        for (int i = 0; i < 10; i++) s += expf(logits[i] - m);
        lsep[0] = m + logf(s);
    }
    __syncthreads();
    if (tid < 10) out[g * 10 + tid] = logits[tid] - lsep[0];
}

extern "C" void kernel_launch(void* const* d_in, const int* in_sizes, int n_in,
                              void* d_out, int out_size, void* d_ws, size_t ws_size,
                              hipStream_t stream) {
    const float* x    = (const float*)d_in[0];
    const int*   ei   = (const int*)d_in[1];
    const float* lmax = (const float*)d_in[3];
    const float* W1   = (const float*)d_in[4];
    const float* b1   = (const float*)d_in[5];
    const float* W2   = (const float*)d_in[6];
    const float* b2   = (const float*)d_in[7];
    const float* W3   = (const float*)d_in[8];
    const float* b3   = (const float*)d_in[9];
    const float* bng  = (const float*)d_in[10];
    const float* bnb  = (const float*)d_in[11];
    const float* bnm  = (const float*)d_in[12];
    const float* bnv  = (const float*)d_in[13];
    const float* fc1w = (const float*)d_in[14];
    const float* fc1b = (const float*)d_in[15];
    const float* fc2w = (const float*)d_in[16];
    const float* fc2b = (const float*)d_in[17];

    const int E = in_sizes[1] / 2;
    const int G = in_sizes[3];
    const int epg = E / G;

    unsigned short* Wt = (unsigned short*)d_ws;

    wconv<<<(WT_TOTAL + 255) / 256, 256, 0, stream>>>(W1, W2, W3, Wt);

    hipFuncSetAttribute((const void*)cheb1b,
                        hipFuncAttributeMaxDynamicSharedMemorySize, SMEM_BYTES);

    cheb1b<<<G, 256, SMEM_BYTES, stream>>>(x, ei, lmax, Wt, b1, b2, b3,
                                           bng, bnb, bnm, bnv, fc1w, fc1b, fc2w, fc2b,
                                           (float*)d_out, E, epg);
}

// Round 8
// 172.016 us; speedup vs baseline: 2.0974x; 1.0747x over previous
//
#include <hip/hip_runtime.h>

#define NPG 100     // nodes per graph
#define HF 64       // hidden width
#define NROW 128    // node rows padded to 4 x 32 tiles
#define ST 72       // Trm row stride (bf16): 64 + 8 pad
#define SAT 136     // Tc row stride (bf16): 128 + 8 pad
#define CMW 28      // count-matrix words per row (112 u8 cols)

typedef float  f4   __attribute__((ext_vector_type(4)));
typedef float  f16v __attribute__((ext_vector_type(16)));
typedef short  bf8  __attribute__((ext_vector_type(8)));

#define SZ_TC  (HF * SAT * 2)         // 17408
#define SZ_TRM (NROW * ST * 2)        // 18432
#define OFF_TC  0
#define OFF_TRM SZ_TC                 // 17408
#define OFF_CM  0                     // u8 counts [128][28 u32] = 14336, overlays Tc (setup only)
#define OFF_MISC (OFF_TRM + SZ_TRM)   // 35840
#define SMEM_BYTES (OFF_MISC + 1280)  // 37120

// bf16 weight workspace (d_ws), layout Wt[k5][fo][fi]:
//   W1t [5][64][16] @ 0  (fi zero-padded 3->16)
//   W2t [5][64][64] @ 5120
//   W3t [5][64][64] @ 25600
#define WT_TOTAL 46080

__device__ __forceinline__ unsigned short f2bf(float f) {
    unsigned u = __float_as_uint(f);
    u += 0x7fffu + ((u >> 16) & 1u);   // round-to-nearest-even
    return (unsigned short)(u >> 16);
}
__device__ __forceinline__ float bf2f(unsigned short h) {
    return __uint_as_float(((unsigned)h) << 16);
}
__device__ __forceinline__ f16v zerov16() {
    f16v z;
    #pragma unroll
    for (int i = 0; i < 16; i++) z[i] = 0.f;
    return z;
}

__global__ void wconv(const float* __restrict__ W1, const float* __restrict__ W2,
                      const float* __restrict__ W3, unsigned short* __restrict__ ws)
{
    int idx = blockIdx.x * 256 + threadIdx.x;
    if (idx >= WT_TOTAL) return;
    float v;
    if (idx < 5120) {
        int k5 = idx >> 10, rem = idx & 1023, fo = rem >> 4, fi = rem & 15;
        v = (fi < 3) ? W1[(k5 * 3 + fi) * HF + fo] : 0.f;
    } else if (idx < 25600) {
        int j = idx - 5120;
        int k5 = j >> 12, rem = j & 4095, fo = rem >> 6, fi = rem & 63;
        v = W2[(k5 * HF + fi) * HF + fo];
    } else {
        int j = idx - 25600;
        int k5 = j >> 12, rem = j & 4095, fo = rem >> 6, fi = rem & 63;
        v = W3[(k5 * HF + fi) * HF + fo];
    }
    ws[idx] = f2bf(v);
}

// One block per graph, 256 threads = 4 waves.
// A-hat fragments live in REGISTERS (af[2][7], built once from u8 count matrix)
// -> no Arm in LDS, no per-stage A-frag reloads.
// Dual-orientation T: Trm [node][f] (TW A-reads b128) + Tc = T^T [f][node]
// (LHAT B-reads b128). LHAT C: col=fo, rows=np quads -> Tc writes are b64;
// Trm writes scalar b16.
// LHAT: C[np][fo] = sum_n Ahat[np][n] * T[n][fo]  (A=af regs, B=Tc rows b128)
// TW:   O[np][fo] += sum_fi T[np][fi] * Wt[fo][fi] (A=Trm rows b128, B=Wt b128)
// C/D: col = lane&31, row = (r&3)+8*(r>>2)+4*(lane>>5)
// Cheb prev/old in packed-bf16 registers. ~190 VGPR live -> (256,2) cap 256,
// no spill (R6 lesson: never use min-waves=3 here).
__launch_bounds__(256, 2)
__global__ void chebreg(const float* __restrict__ x, const int* __restrict__ ei,
                        const float* __restrict__ lambda_max,
                        const unsigned short* __restrict__ Wt,
                        const float* __restrict__ b1, const float* __restrict__ b2,
                        const float* __restrict__ b3,
                        const float* __restrict__ bng, const float* __restrict__ bnb,
                        const float* __restrict__ bnm, const float* __restrict__ bnv,
                        const float* __restrict__ fc1w, const float* __restrict__ fc1b,
                        const float* __restrict__ fc2w, const float* __restrict__ fc2b,
                        float* __restrict__ out, int E_total, int epg)
{
    extern __shared__ char sm[];
    const int tid = threadIdx.x;
    const int g = blockIdx.x;
    const int ebase = g * epg, nbase = g * NPG;
    const int wg = tid >> 6, lane = tid & 63;
    const int l31 = lane & 31, hh = lane >> 5;
    const int ht  = wg & 1;          // f-tile: cols 32*ht..+31
    const int Mt0 = (wg >> 1) * 2;   // n'-tile pair base
    const int fo  = ht * 32 + l31;

    unsigned* Cm  = (unsigned*)(sm + OFF_CM);
    float* dis    = (float*)(sm + OFF_MISC);          // 448 B (112 entries)
    float* pool   = (float*)(sm + OFF_MISC + 448);    // 256 B
    float* gvn    = (float*)(sm + OFF_MISC + 704);    // 256 B
    float* zf     = (float*)(sm + OFF_MISC + 960);    // 128 B
    float* logits = (float*)(sm + OFF_MISC + 1088);   // 64 B
    float* lsep   = (float*)(sm + OFF_MISC + 1152);

    const float lam = lambda_max[g];
    const float two_l = 2.0f / lam;
    const float cl = two_l - 1.0f;

    // ---------------- u8 count matrix + dis ----------------
    for (int i = tid; i < (NROW * CMW) / 4; i += 256)
        ((f4*)Cm)[i] = (f4){0.f, 0.f, 0.f, 0.f};
    __syncthreads();
    for (int e = tid; e < epg; e += 256) {
        int r = ei[ebase + e] - nbase;
        int c = ei[E_total + ebase + e] - nbase;
        atomicAdd(&Cm[r * CMW + (c >> 2)], 1u << (8 * (c & 3)));
    }
    __syncthreads();
    if (tid < 112) {
        float dv = 0.f;
        if (tid < NPG) {
            unsigned s = 0;
            #pragma unroll
            for (int w = 0; w < CMW; w++) {
                unsigned u = Cm[tid * CMW + w];
                s += (u & 255) + ((u >> 8) & 255) + ((u >> 16) & 255) + (u >> 24);
            }
            dv = s > 0 ? rsqrtf((float)s) : 0.f;
        }
        dis[tid] = dv;
    }
    __syncthreads();

    // ---------------- A-hat fragments -> registers (once) ----------------
    bf8 af[2][7];
    #pragma unroll
    for (int m = 0; m < 2; m++) {
        int rr = 32 * (Mt0 + m) + l31;
        bool rv = (rr < NPG);
        float base = rv ? (-two_l * dis[rr]) : 0.f;
        #pragma unroll
        for (int Ks = 0; Ks < 7; Ks++) {
            int k0 = Ks * 16 + 8 * hh;
            unsigned w0 = rv ? Cm[rr * CMW + (k0 >> 2)]     : 0u;
            unsigned w1 = rv ? Cm[rr * CMW + (k0 >> 2) + 1] : 0u;
            #pragma unroll
            for (int j = 0; j < 8; j++) {
                int k = k0 + j;
                unsigned cnt = (((j < 4) ? w0 : w1) >> (8 * (k & 3))) & 255u;
                float v = base * (float)cnt * dis[k];
                if (rv && k == rr) v += cl;
                af[m][Ks][j] = (short)f2bf(v);
            }
        }
    }
    __syncthreads();   // Cm reads done before Tc (overlay) is zeroed

    // ---------------- init Tc + Trm: zero + x ----------------
    for (int i = tid; i < (SZ_TC + SZ_TRM) / 16; i += 256)
        ((f4*)sm)[i] = (f4){0.f, 0.f, 0.f, 0.f};
    if (tid < HF) pool[tid] = 0.f;
    __syncthreads();
    if (tid < NPG) {
        unsigned short h0 = f2bf(x[(nbase + tid) * 3 + 0]);
        unsigned short h1 = f2bf(x[(nbase + tid) * 3 + 1]);
        unsigned short h2 = f2bf(x[(nbase + tid) * 3 + 2]);
        *(unsigned*)(sm + OFF_TRM + (tid * ST) * 2) = (unsigned)h0 | ((unsigned)h1 << 16);
        *(unsigned short*)(sm + OFF_TRM + (tid * ST + 2) * 2) = h2;
        *(unsigned short*)(sm + OFF_TC + (0 * SAT + tid) * 2) = h0;
        *(unsigned short*)(sm + OFF_TC + (1 * SAT + tid) * 2) = h1;
        *(unsigned short*)(sm + OFF_TC + (2 * SAT + tid) * 2) = h2;
    }
    __syncthreads();

    // ---------------- 3 ChebConv layers ----------------
    f16v acc[2];
    unsigned prev[2][8], oldr[2][8];   // packed-bf16 T_{s-1}, T_{s-2} at (np, fo) lane positions
    const float* bsv[3] = {b1, b2, b3};

    for (int L = 0; L < 3; L++) {
        const bool l1 = (L == 0);
        const unsigned short* Wl = l1 ? Wt : (Wt + (L == 1 ? 5120 : 25600));
        acc[0] = zerov16();
        acc[1] = zerov16();

        // prev = T0 at C-layout positions
        #pragma unroll
        for (int m = 0; m < 2; m++) {
            unsigned short tv[16];
            #pragma unroll
            for (int r = 0; r < 16; r++) {
                int np = (Mt0 + m) * 32 + (r & 3) + 8 * (r >> 2) + 4 * hh;
                tv[r] = *(const unsigned short*)(sm + OFF_TRM + (np * ST + fo) * 2);
            }
            #pragma unroll
            for (int p = 0; p < 8; p++)
                prev[m][p] = (unsigned)tv[2 * p] | ((unsigned)tv[2 * p + 1] << 16);
        }

        auto TW = [&](int k5) {
            const int nKs = l1 ? 1 : 4;
            for (int Ks = 0; Ks < nKs; Ks++) {
                bf8 bw;
                if (l1) bw = *(const bf8*)(Wl + (k5 * 64 + fo) * 16 + 8 * hh);
                else    bw = *(const bf8*)(Wl + (k5 * 64 + fo) * 64 + Ks * 16 + 8 * hh);
                #pragma unroll
                for (int m = 0; m < 2; m++) {
                    bf8 a = *(const bf8*)(sm + OFF_TRM +
                              (((Mt0 + m) * 32 + l31) * ST + Ks * 16 + 8 * hh) * 2);
                    acc[m] = __builtin_amdgcn_mfma_f32_32x32x16_bf16(a, bw, acc[m], 0, 0, 0);
                }
            }
        };

        TW(0);
        for (int s = 1; s <= 4; s++) {
            // B-frags: Tc rows (this lane's fo column set), b128
            bf8 bfr[7];
            #pragma unroll
            for (int Ks = 0; Ks < 7; Ks++)
                bfr[Ks] = *(const bf8*)(sm + OFF_TC +
                            (fo * SAT + Ks * 16 + 8 * hh) * 2);
            __syncthreads();   // all T reads (TW(s-1), prev-init, bfr) done
            #pragma unroll
            for (int m = 0; m < 2; m++) {
                f16v c = zerov16();
                #pragma unroll
                for (int Ks = 0; Ks < 7; Ks++)
                    c = __builtin_amdgcn_mfma_f32_32x32x16_bf16(af[m][Ks], bfr[Ks], c, 0, 0, 0);
                unsigned short h[16];
                #pragma unroll
                for (int r = 0; r < 16; r++) {
                    float v = c[r];
                    if (s >= 2) {
                        unsigned short o = (unsigned short)
                            ((oldr[m][r >> 1] >> (16 * (r & 1))) & 0xffff);
                        v = 2.f * v - bf2f(o);
                    }
                    h[r] = f2bf(v);
                }
                #pragma unroll
                for (int p = 0; p < 8; p++) {
                    oldr[m][p] = prev[m][p];
                    prev[m][p] = (unsigned)h[2 * p] | ((unsigned)h[2 * p + 1] << 16);
                }
                // Tc writes: node-quads contiguous -> 4x b64
                #pragma unroll
                for (int q4 = 0; q4 < 4; q4++) {
                    int np0 = (Mt0 + m) * 32 + 8 * q4 + 4 * hh;
                    uint2 pk;
                    pk.x = prev[m][2 * q4];
                    pk.y = prev[m][2 * q4 + 1];
                    *(uint2*)(sm + OFF_TC + (fo * SAT + np0) * 2) = pk;
                }
                // Trm writes: scalar b16 x16
                #pragma unroll
                for (int r = 0; r < 16; r++) {
                    int np = (Mt0 + m) * 32 + (r & 3) + 8 * (r >> 2) + 4 * hh;
                    *(unsigned short*)(sm + OFF_TRM + (np * ST + fo) * 2) = h[r];
                }
            }
            __syncthreads();   // writes visible before TW(s)
            TW(s);
        }
        __syncthreads();       // TW(4) reads done before epilogue writes

        const float bias = bsv[L][fo];
        if (L < 2) {
            #pragma unroll
            for (int m = 0; m < 2; m++) {
                unsigned short h[16];
                #pragma unroll
                for (int r = 0; r < 16; r++) {
                    h[r] = f2bf(fmaxf(acc[m][r] + bias, 0.f));
                    int np = (Mt0 + m) * 32 + (r & 3) + 8 * (r >> 2) + 4 * hh;
                    *(unsigned short*)(sm + OFF_TRM + (np * ST + fo) * 2) = h[r];
                }
                #pragma unroll
                for (int q4 = 0; q4 < 4; q4++) {
                    int np0 = (Mt0 + m) * 32 + 8 * q4 + 4 * hh;
                    uint2 pk;
                    pk.x = (unsigned)h[4 * q4]     | ((unsigned)h[4 * q4 + 1] << 16);
                    pk.y = (unsigned)h[4 * q4 + 2] | ((unsigned)h[4 * q4 + 3] << 16);
                    *(uint2*)(sm + OFF_TC + (fo * SAT + np0) * 2) = pk;
                }
            }
            __syncthreads();
        } else {
            float ssum = 0.f;
            #pragma unroll
            for (int m = 0; m < 2; m++) {
                #pragma unroll
                for (int r = 0; r < 16; r++) {
                    int np = (Mt0 + m) * 32 + (r & 3) + 8 * (r >> 2) + 4 * hh;
                    float h = fmaxf(acc[m][r] + bias, 0.f);
                    if (np < NPG) ssum += h;
                }
            }
            ssum += __shfl_xor(ssum, 32, 64);
            if (hh == 0) atomicAdd(&pool[fo], ssum);
            __syncthreads();
        }
    }

    // ---------------- BN + MLP + log_softmax ----------------
    if (tid < HF) {
        float gv = pool[tid] * (1.0f / NPG);
        gv = (gv - bnm[tid]) * rsqrtf(bnv[tid] + 1e-5f) * bng[tid] + bnb[tid];
        gvn[tid] = gv;
    }
    __syncthreads();
    if (tid < 32) {
        float a = fc1b[tid];
        for (int f = 0; f < HF; f++) a += gvn[f] * fc1w[f * 32 + tid];
        zf[tid] = fmaxf(a, 0.f);
    }
    __syncthreads();
    if (tid < 10) {
        float a = fc2b[tid];
        for (int k = 0; k < 32; k++) a += zf[k] * fc2w[k * 10 + tid];
        logits[tid] = a;
    }
    __syncthreads();
    if (tid == 0) {
        float m = logits[0];
        for (int i = 1; i < 10; i++) m = fmaxf(m, logits[i]);
        float s = 0.f;
        for (int i = 0; i < 10; i++) s += expf(logits[i] - m);
        lsep[0] = m + logf(s);
    }
    __syncthreads();
    if (tid < 10) out[g * 10 + tid] = logits[tid] - lsep[0];
}

extern "C" void kernel_launch(void* const* d_in, const int* in_sizes, int n_in,
                              void* d_out, int out_size, void* d_ws, size_t ws_size,
                              hipStream_t stream) {
    const float* x    = (const float*)d_in[0];
    const int*   ei   = (const int*)d_in[1];
    const float* lmax = (const float*)d_in[3];
    const float* W1   = (const float*)d_in[4];
    const float* b1   = (const float*)d_in[5];
    const float* W2   = (const float*)d_in[6];
    const float* b2   = (const float*)d_in[7];
    const float* W3   = (const float*)d_in[8];
    const float* b3   = (const float*)d_in[9];
    const float* bng  = (const float*)d_in[10];
    const float* bnb  = (const float*)d_in[11];
    const float* bnm  = (const float*)d_in[12];
    const float* bnv  = (const float*)d_in[13];
    const float* fc1w = (const float*)d_in[14];
    const float* fc1b = (const float*)d_in[15];
    const float* fc2w = (const float*)d_in[16];
    const float* fc2b = (const float*)d_in[17];

    const int E = in_sizes[1] / 2;
    const int G = in_sizes[3];
    const int epg = E / G;

    unsigned short* Wt = (unsigned short*)d_ws;

    wconv<<<(WT_TOTAL + 255) / 256, 256, 0, stream>>>(W1, W2, W3, Wt);

    hipFuncSetAttribute((const void*)chebreg,
                        hipFuncAttributeMaxDynamicSharedMemorySize, SMEM_BYTES);

    chebreg<<<G, 256, SMEM_BYTES, stream>>>(x, ei, lmax, Wt, b1, b2, b3,
                                            bng, bnb, bnm, bnv, fc1w, fc1b, fc2w, fc2b,
                                            (float*)d_out, E, epg);
}